// Round 1
// 4242.009 us; speedup vs baseline: 2.4569x; 2.4569x over previous
//
#include <hip/hip_runtime.h>

#define BB 100000
#define NN 20
#define ND 128
#define TD 64
#define CD 192
#define HD 128
#define NH 4
#define DH 32
#define NL 2
#define G 4
#define T 512
#define KCS 196   // padded kc row stride (bf16 elements): 392B rows, 8B aligned
#define RUS 772   // padded r/u row stride (floats): 16B aligned, banks spread

static_assert(BB % G == 0, "grid must divide B");

static __device__ __forceinline__ float bf2f(unsigned short u) {
  return __uint_as_float(((unsigned)u) << 16);
}
static __device__ __forceinline__ unsigned short f2bf(float x) {
  unsigned b = __float_as_uint(x);
  return (unsigned short)((b + 0x7FFFu + ((b >> 16) & 1u)) >> 16);
}

// scores_h(n) = q_h . (kcomb_n @ Wk_h)  with q = qcomb@Wq + bq.
// (bk contributes an n-uniform shift -> softmax-invariant -> dropped.)
// Rank-32 factorization: r_h = q_h @ Wk_h^T  (2*CD*DH MACs) instead of the
// old dense M = Wq Wk^T fold (CD*CD MACs) -- 3x fewer FLOPs, no bf16 M.
__global__ __launch_bounds__(T, 4) void tgat_fused(
    const float* __restrict__ nf, const float* __restrict__ nbf,
    const float* __restrict__ nt, const float* __restrict__ nbt,
    const float* __restrict__ tf, const float* __restrict__ tp,
    const float* __restrict__ Wq, const float* __restrict__ bq,
    const float* __restrict__ Wk,
    const float* __restrict__ Wv, const float* __restrict__ bv,
    const float* __restrict__ Wo, const float* __restrict__ bo,
    const float* __restrict__ W1, const float* __restrict__ b1,
    const float* __restrict__ W2, const float* __restrict__ b2,
    const float* __restrict__ g1, const float* __restrict__ be1,
    const float* __restrict__ g2, const float* __restrict__ be2,
    const float* __restrict__ Wc1, const float* __restrict__ bc1,
    const float* __restrict__ Wc2, const float* __restrict__ bc2,
    const int* __restrict__ mask,
    float* __restrict__ out) {
  __shared__ __align__(16) unsigned short kc[G][NN][KCS]; // kcomb bf16
  __shared__ __align__(16) float xs[G][ND];
  __shared__ __align__(16) float tqs[G][TD];
  __shared__ __align__(16) float ys[G][HD];   // q projection
  __shared__ __align__(16) float rs[G][RUS];  // r = q @ Wk^T
  __shared__ __align__(16) float us[G][RUS];  // u = w @ kcomb
  __shared__ __align__(16) float scs[G][NH][NN];
  __shared__ __align__(16) float as_[G][HD];
  __shared__ __align__(16) float ffs[G][ND];
  __shared__ __align__(16) float h1s[G][2 * ND];
  __shared__ int msks[G][NN];

  const int tid = threadIdx.x;
  const int b0 = blockIdx.x * G;

  // ---- stage per-element data (once; reused by both layers) ----
  for (int idx = tid; idx < G * ND; idx += T) {
    int g = idx >> 7, j = idx & 127;
    xs[g][j] = nf[(b0 + g) * ND + j];
  }
  for (int idx = tid; idx < G * TD; idx += T) {
    int g = idx >> 6, j = idx & 63;
    tqs[g][j] = cosf(nt[b0 + g] * tf[j] + tp[j]);
  }
  for (int idx = tid; idx < G * NN; idx += T) {
    int g = idx / NN, n = idx % NN;
    msks[g][n] = mask[(b0 + g) * NN + n];
  }
  // neighbor features -> kc (vectorized float4 -> ushort4)
  for (int idx = tid; idx < G * NN * (ND / 4); idx += T) {
    int g = idx / (NN * (ND / 4));
    int rem = idx % (NN * (ND / 4));
    int n = rem >> 5, cq = rem & 31;
    float4 v = *(const float4*)&nbf[(((b0 + g) * NN + n) * ND) + cq * 4];
    ushort4 o;
    o.x = f2bf(v.x); o.y = f2bf(v.y); o.z = f2bf(v.z); o.w = f2bf(v.w);
    *(ushort4*)&kc[g][n][cq * 4] = o;
  }
  for (int idx = tid; idx < G * NN * TD; idx += T) {
    int g = idx / (NN * TD), rem = idx % (NN * TD);
    int n = rem >> 6, j = rem & 63;
    kc[g][n][ND + j] = f2bf(cosf(nbt[(b0 + g) * NN + n] * tf[j] + tp[j]));
  }
  __syncthreads();

  const float scale = 0.17677669529663687f; // 1/sqrt(32)

  for (int l = 0; l < NL; ++l) {
    // ---- y = qcomb @ Wq + bq : exactly one output per thread ----
    {
      int g = tid >> 7, j = tid & 127;
      const float* wq = Wq + (l * CD) * HD + j;
      float acc = bq[l * HD + j];
      for (int c = 0; c < CD; c += 4) {
        float4 qv = (c < ND) ? *(const float4*)&xs[g][c]
                             : *(const float4*)&tqs[g][c - ND];
        acc += qv.x * wq[(c + 0) * HD] + qv.y * wq[(c + 1) * HD] +
               qv.z * wq[(c + 2) * HD] + qv.w * wq[(c + 3) * HD];
      }
      ys[g][j] = acc;
    }
    __syncthreads();
    // ---- r[g][h*CD+c2] = sum_d y[g][h][d] * Wk[c2][h*32+d] ----
    // 768 (h,c2) x 2 g-pairs = 1536 units, 3 per thread (balanced).
    for (int rep = 0; rep < 3; ++rep) {
      int uu = rep * T + tid;       // 0..1535
      int i = uu >> 1;              // 0..767 = h*CD + c2
      int gp = (uu & 1) << 1;       // 0 or 2
      int h = i / CD;
      int c2 = i - h * CD;
      const float* wk = Wk + (l * CD + c2) * HD + h * DH;
      const float* yp0 = &ys[gp][h * DH];
      const float* yp1 = &ys[gp + 1][h * DH];
      float a0 = 0.f, a1 = 0.f;
#pragma unroll
      for (int d = 0; d < DH; d += 4) {
        float4 w4 = *(const float4*)&wk[d];
        float4 y0 = *(const float4*)&yp0[d];
        float4 y1 = *(const float4*)&yp1[d];
        a0 += y0.x * w4.x + y0.y * w4.y + y0.z * w4.z + y0.w * w4.w;
        a1 += y1.x * w4.x + y1.y * w4.y + y1.z * w4.z + y1.w * w4.w;
      }
      rs[gp][i] = a0;
      rs[gp + 1][i] = a1;
    }
    __syncthreads();
    // ---- scores[g][h][n] = scale * r_h . kcomb_n (masked -> -1e9) ----
    for (int idx = tid; idx < G * NH * NN; idx += T) {
      int g = idx / (NH * NN), rem = idx % (NH * NN);
      int h = rem / NN, n = rem % NN;
      const float* rp = &rs[g][h * CD];
      const unsigned short* kp = &kc[g][n][0];
      float acc = 0.f;
      for (int c = 0; c < CD; c += 4) {
        float4 rv = *(const float4*)&rp[c];
        ushort4 kv = *(const ushort4*)&kp[c];
        acc += rv.x * bf2f(kv.x) + rv.y * bf2f(kv.y) +
               rv.z * bf2f(kv.z) + rv.w * bf2f(kv.w);
      }
      scs[g][h][n] = msks[g][n] ? acc * scale : -1e9f;
    }
    __syncthreads();
    // ---- softmax per (g,h) ----
    if (tid < G * NH) {
      int g = tid / NH, h = tid % NH;
      float mx = -3.4e38f;
#pragma unroll
      for (int n = 0; n < NN; ++n) mx = fmaxf(mx, scs[g][h][n]);
      float ev[NN];
      float s = 0.f;
#pragma unroll
      for (int n = 0; n < NN; ++n) { ev[n] = expf(scs[g][h][n] - mx); s += ev[n]; }
      float inv = 1.f / s;
#pragma unroll
      for (int n = 0; n < NN; ++n) scs[g][h][n] = ev[n] * inv;
    }
    __syncthreads();
    // ---- u[g][h][c] = sum_n w[g][h][n] * kcomb[g][n][c] : 768 quads ----
    for (int flat = tid; flat < G * NH * (CD / 4); flat += T) {
      int g = flat / (NH * (CD / 4));
      int iq = flat % (NH * (CD / 4));
      int h = iq / (CD / 4);
      int c = (iq % (CD / 4)) * 4;
      const unsigned short* kp = &kc[g][0][0];
      float a0 = 0.f, a1 = 0.f, a2 = 0.f, a3 = 0.f;
#pragma unroll
      for (int n = 0; n < NN; ++n) {
        float w = scs[g][h][n];
        ushort4 kv = *(const ushort4*)&kp[n * KCS + c];
        a0 += w * bf2f(kv.x); a1 += w * bf2f(kv.y);
        a2 += w * bf2f(kv.z); a3 += w * bf2f(kv.w);
      }
      *(float4*)&us[g][h * CD + c] = make_float4(a0, a1, a2, a3);
    }
    __syncthreads();
    // ---- a = u @ Wv + bv : one output per thread ----
    {
      int j = tid & (HD - 1);
      int g = tid >> 7;
      int h = j >> 5;
      const float* wv = Wv + (l * CD) * HD + j;
      float acc = 0.f;
      for (int c = 0; c < CD; c += 4) {
        float4 uv = *(const float4*)&us[g][h * CD + c];
        acc += uv.x * wv[(c + 0) * HD] + uv.y * wv[(c + 1) * HD] +
               uv.z * wv[(c + 2) * HD] + uv.w * wv[(c + 3) * HD];
      }
      as_[g][j] = acc + bv[l * HD + j];
    }
    __syncthreads();
    // ---- attn = a @ Wo + bo -> ffs ----
    {
      int j = tid & (ND - 1);
      int g = tid >> 7;
      const float* wo = Wo + (l * HD) * ND + j;
      float acc = 0.f;
      for (int c = 0; c < HD; c += 4) {
        float4 av = *(const float4*)&as_[g][c];
        acc += av.x * wo[(c + 0) * ND] + av.y * wo[(c + 1) * ND] +
               av.z * wo[(c + 2) * ND] + av.w * wo[(c + 3) * ND];
      }
      ffs[g][j] = acc + bo[l * ND + j];
    }
    __syncthreads();
    // ---- LN1: wave g (of first 4 waves) owns element g ----
    if (tid < G * 64) {
      int g = tid >> 6, lane = tid & 63;
      float y0 = xs[g][lane] + ffs[g][lane];
      float y1 = xs[g][lane + 64] + ffs[g][lane + 64];
      float s = y0 + y1, ss = y0 * y0 + y1 * y1;
#pragma unroll
      for (int off = 32; off > 0; off >>= 1) {
        s += __shfl_xor(s, off);
        ss += __shfl_xor(ss, off);
      }
      float mean = s * (1.f / ND);
      float var = ss * (1.f / ND) - mean * mean;
      float rstd = rsqrtf(var + 1e-5f);
      xs[g][lane] = (y0 - mean) * rstd * g1[l * ND + lane] + be1[l * ND + lane];
      xs[g][lane + 64] =
          (y1 - mean) * rstd * g1[l * ND + lane + 64] + be1[l * ND + lane + 64];
    }
    __syncthreads();
    // ---- FF1: h1 = relu(x @ W1 + b1) : 2 outputs per thread ----
    {
      int j = tid & (2 * ND - 1);
      int gq = tid >> 8;  // 0..1, handles g = gq and gq+2
      const float* w1p = W1 + (l * ND) * (2 * ND) + j;
      float acc0 = 0.f, acc1 = 0.f;
      for (int c = 0; c < ND; c += 4) {
        float w0 = w1p[(c + 0) * 2 * ND], wa = w1p[(c + 1) * 2 * ND],
              w2 = w1p[(c + 2) * 2 * ND], w3 = w1p[(c + 3) * 2 * ND];
        float4 x0 = *(const float4*)&xs[gq][c];
        float4 x1 = *(const float4*)&xs[gq + 2][c];
        acc0 += x0.x * w0 + x0.y * wa + x0.z * w2 + x0.w * w3;
        acc1 += x1.x * w0 + x1.y * wa + x1.z * w2 + x1.w * w3;
      }
      float b1v = b1[l * 2 * ND + j];
      h1s[gq][j] = fmaxf(acc0 + b1v, 0.f);
      h1s[gq + 2][j] = fmaxf(acc1 + b1v, 0.f);
    }
    __syncthreads();
    // ---- FF2 -> ffs : one output per thread ----
    {
      int j = tid & (ND - 1);
      int g = tid >> 7;
      const float* w2p = W2 + (l * 2 * ND) * ND + j;
      float acc = 0.f;
      for (int c = 0; c < 2 * ND; c += 4) {
        float4 hv = *(const float4*)&h1s[g][c];
        acc += hv.x * w2p[(c + 0) * ND] + hv.y * w2p[(c + 1) * ND] +
               hv.z * w2p[(c + 2) * ND] + hv.w * w2p[(c + 3) * ND];
      }
      ffs[g][j] = acc + b2[l * ND + j];
    }
    __syncthreads();
    // ---- LN2 ----
    if (tid < G * 64) {
      int g = tid >> 6, lane = tid & 63;
      float y0 = xs[g][lane] + ffs[g][lane];
      float y1 = xs[g][lane + 64] + ffs[g][lane + 64];
      float s = y0 + y1, ss = y0 * y0 + y1 * y1;
#pragma unroll
      for (int off = 32; off > 0; off >>= 1) {
        s += __shfl_xor(s, off);
        ss += __shfl_xor(ss, off);
      }
      float mean = s * (1.f / ND);
      float var = ss * (1.f / ND) - mean * mean;
      float rstd = rsqrtf(var + 1e-5f);
      xs[g][lane] = (y0 - mean) * rstd * g2[l * ND + lane] + be2[l * ND + lane];
      xs[g][lane + 64] =
          (y1 - mean) * rstd * g2[l * ND + lane + 64] + be2[l * ND + lane + 64];
    }
    __syncthreads();
  }
  // ---- classifier: relu(x@Wc1+bc1) in scs scratch, then sigmoid(h@Wc2+bc2) ----
  if (tid < G * 64) {
    int j = tid & 63;
    int g = tid >> 6;
    const float* wc = Wc1 + j;
    float acc = 0.f;
    for (int c = 0; c < ND; c += 4) {
      float4 xv = *(const float4*)&xs[g][c];
      acc += xv.x * wc[(c + 0) * 64] + xv.y * wc[(c + 1) * 64] +
             xv.z * wc[(c + 2) * 64] + xv.w * wc[(c + 3) * 64];
    }
    ((float*)scs)[g * 64 + j] = fmaxf(acc + bc1[j], 0.f);
  }
  __syncthreads();
  if (tid < G * 64) {
    int g = tid >> 6, lane = tid & 63;
    float p = ((float*)scs)[g * 64 + lane] * Wc2[lane];
#pragma unroll
    for (int off = 32; off > 0; off >>= 1) p += __shfl_xor(p, off);
    if (lane == 0) {
      float z = p + bc2[0];
      out[b0 + g] = 1.f / (1.f + expf(-z));
    }
  }
}

extern "C" void kernel_launch(void* const* d_in, const int* in_sizes, int n_in,
                              void* d_out, int out_size, void* d_ws, size_t ws_size,
                              hipStream_t stream) {
  (void)in_sizes; (void)n_in; (void)out_size; (void)d_ws; (void)ws_size;
  const float* nf  = (const float*)d_in[0];
  const float* nbf = (const float*)d_in[1];
  const float* nt  = (const float*)d_in[2];
  const float* nbt = (const float*)d_in[3];
  const float* tf  = (const float*)d_in[4];
  const float* tp  = (const float*)d_in[5];
  const float* Wq  = (const float*)d_in[6];
  const float* bq  = (const float*)d_in[7];
  const float* Wk  = (const float*)d_in[8];
  // d_in[9] = bk: only contributes n-uniform score shifts -> softmax-invariant
  const float* Wv  = (const float*)d_in[10];
  const float* bv  = (const float*)d_in[11];
  const float* Wo  = (const float*)d_in[12];
  const float* bo  = (const float*)d_in[13];
  const float* W1  = (const float*)d_in[14];
  const float* b1  = (const float*)d_in[15];
  const float* W2  = (const float*)d_in[16];
  const float* b2  = (const float*)d_in[17];
  const float* g1  = (const float*)d_in[18];
  const float* be1 = (const float*)d_in[19];
  const float* g2  = (const float*)d_in[20];
  const float* be2 = (const float*)d_in[21];
  const float* Wc1 = (const float*)d_in[22];
  const float* bc1 = (const float*)d_in[23];
  const float* Wc2 = (const float*)d_in[24];
  const float* bc2 = (const float*)d_in[25];
  const int* mask  = (const int*)d_in[26];
  float* out = (float*)d_out;

  tgat_fused<<<BB / G, T, 0, stream>>>(nf, nbf, nt, nbt, tf, tp, Wq, bq, Wk,
                                       Wv, bv, Wo, bo, W1, b1, W2, b2, g1, be1,
                                       g2, be2, Wc1, bc1, Wc2, bc2, mask, out);
}